// Round 13
// baseline (555.484 us; speedup 1.0000x reference)
//
#include <hip/hip_runtime.h>
#include <math.h>

__device__ __forceinline__ float lrelu(float x){ return x > 0.0f ? x : 0.2f*x; }
__device__ __forceinline__ float bcastf(float v, int l){
    return __int_as_float(__builtin_amdgcn_readlane(__float_as_int(v), l));
}

// ---------------- precompute ----------------

__global__ void k_count(const int* __restrict__ dst, int* __restrict__ cnt, int E){
    int e = blockIdx.x*256 + threadIdx.x;
    if(e < E) atomicAdd(&cnt[dst[e]], 1);
}

__global__ __launch_bounds__(1024) void k_scan(const int* __restrict__ cnt, int* __restrict__ rowptr, int n){
    __shared__ int ws[16];
    __shared__ int carrysh;
    int t = threadIdx.x, lane = t & 63, wv = t >> 6;
    if(t==0){ carrysh = 0; rowptr[0] = 0; }
    __syncthreads();
    for(int base=0; base<n; base+=1024){
        int i = base + t;
        int v = (i<n) ? cnt[i] : 0;
        int s = v;
        #pragma unroll
        for(int off=1; off<64; off<<=1){ int u = __shfl_up(s, off, 64); if(lane>=off) s += u; }
        if(lane==63) ws[wv] = s;
        __syncthreads();
        if(t < 16){
            int u = ws[t];
            #pragma unroll
            for(int off=1; off<16; off<<=1){ int u2 = __shfl_up(u, off, 16); if(t>=off) u += u2; }
            ws[t] = u;
        }
        __syncthreads();
        int carry = carrysh;
        int wbase = wv ? ws[wv-1] : 0;
        if(i<n) rowptr[i+1] = carry + wbase + s;
        int total = ws[15];
        __syncthreads();
        if(t==0) carrysh = carry + total;
        __syncthreads();
    }
}

__global__ void k_scatter(const int* __restrict__ dst, const int* __restrict__ rowptr,
                          int* __restrict__ cnt2, int* __restrict__ eid, int E){
    int e = blockIdx.x*256 + threadIdx.x;
    if(e >= E) return;
    int d = dst[e];
    int p = rowptr[d] + atomicAdd(&cnt2[d], 1);
    eid[p] = e;
}

__global__ __launch_bounds__(256) void k_sortb(const int* __restrict__ rowptr, int* __restrict__ eid, int n){
    int node = blockIdx.x*4 + (threadIdx.x>>6);
    if(node >= n) return;
    int lane = threadIdx.x & 63;
    int b = rowptr[node], e = rowptr[node+1];
    int nj = e - b;
    if(nj <= 1) return;
    if(nj <= 64){
        int v = (lane < nj) ? eid[b+lane] : 0x7fffffff;
        for(int k=2; k<=64; k<<=1){
            for(int j=k>>1; j>0; j>>=1){
                int vv = __shfl_xor(v, j, 64);
                bool up = ((lane & k) == 0);
                bool lower = ((lane & j) == 0);
                int mn = min(v,vv), mx = max(v,vv);
                v = (lower == up) ? mn : mx;
            }
        }
        if(lane < nj) eid[b+lane] = v;
    } else if(lane == 0){
        for(int i=b+1; i<e; i++){
            int key = eid[i]; int j = i-1;
            while(j>=b && eid[j] > key){ eid[j+1] = eid[j]; j--; }
            eid[j+1] = key;
        }
    }
}

// T[l][a] = emb[a] . wvec[l]
__global__ __launch_bounds__(768) void k_table(const float* __restrict__ We, const float* __restrict__ atte,
                                               const float* __restrict__ emb, float* __restrict__ T){
    __shared__ float wv[768];
    int t = threadIdx.x;
    {
        int l = t>>7, k = t&127;
        const float* w = We + ((size_t)l*128 + k)*64;
        const float* a = atte + l*64;
        float s = 0.f;
        #pragma unroll 8
        for(int c=0;c<64;c++) s += w[c]*a[c];
        wv[t] = s;
    }
    __syncthreads();
    int l = t>>7, a = t&127;
    const float4* er = (const float4*)(emb + (size_t)a*128);
    const float* w = wv + l*128;
    float acc = 0.f;
    for(int k=0;k<32;k++){
        float4 v = er[k];
        acc += v.x*w[k*4+0] + v.y*w[k*4+1] + v.z*w[k*4+2] + v.w*w[k*4+3];
    }
    T[l*128 + a] = acc;
}

// fill csrsrc + ae[l][p] by table lookup (pure gather)
__global__ __launch_bounds__(256) void k_ae2(const int* __restrict__ eid, const int* __restrict__ src,
                     const int* __restrict__ eattr, const float* __restrict__ T,
                     int* __restrict__ csrsrc, float* __restrict__ ae, int E){
    __shared__ float Tl[768];
    for(int i=threadIdx.x; i<768; i+=256) Tl[i] = T[i];
    __syncthreads();
    int p = blockIdx.x*256 + threadIdx.x;
    if(p >= E) return;
    int e = eid[p];
    csrsrc[p] = src[e];
    int a = eattr[e];
    #pragma unroll
    for(int l=0;l<6;l++) ae[(size_t)l*E + p] = Tl[l*128 + a];
}

// Wcomb[l] = W3[l] @ Wn[l+1]  (64x64, l=0..4); bcomb[l] = b3[l] @ Wn[l+1]
__global__ __launch_bounds__(256) void k_wcomb(const float* __restrict__ W3all, const float* __restrict__ Wnall,
                                               const float* __restrict__ b3all,
                                               float* __restrict__ Wcomb, float* __restrict__ bcomb){
    int l = blockIdx.x;                               // 0..4
    const float* W3 = W3all + (size_t)l*8192;
    const float* Wn = Wnall + (size_t)(l+1)*8192;
    const float* b3 = b3all + l*128;
    float* Wc = Wcomb + l*4096;
    int t = threadIdx.x;
    for(int q=0;q<16;q++){
        int o = t*16 + q;
        int k = o>>6, c = o&63;
        float s = 0.f;
        for(int j=0;j<128;j++) s += W3[k*128+j]*Wn[j*64+c];
        Wc[k*64+c] = s;
    }
    if(t < 64){
        float s = 0.f;
        for(int j=0;j<128;j++) s += b3[j]*Wn[j*64+t];
        bcomb[l*64+t] = s;
    }
}

// hemb[a][c] = emb[a] @ conv_W[0]  — sequential-k order identical to old k_hx (bit-exact)
__global__ __launch_bounds__(512) void k_hemb(const float* __restrict__ emb, const float* __restrict__ W0,
                                              float* __restrict__ hemb){
    int t = threadIdx.x;
    int a = t>>2, c0 = (t&3)*16;
    const float* er = emb + (size_t)a*128;
    float acc[16];
    #pragma unroll
    for(int cc=0;cc<16;cc++) acc[cc] = 0.f;
    for(int k=0;k<128;k++){
        float xv = er[k];
        #pragma unroll
        for(int cc=0;cc<16;cc++) acc[cc] = fmaf(xv, W0[k*64 + c0 + cc], acc[cc]);
    }
    #pragma unroll
    for(int cc=0;cc<16;cc++) hemb[a*64 + c0 + cc] = acc[cc];
}

// aS[a]/aD[a] with the old k_hx's 8-chunk reduction order (bit-exact)
__global__ __launch_bounds__(128) void k_aemb(const float* __restrict__ hemb,
                                              const float* __restrict__ atts, const float* __restrict__ attd,
                                              float* __restrict__ aS, float* __restrict__ aD){
    int a = threadIdx.x;                              // 0..127
    const float* hr = hemb + a*64;
    float sa = 0.f, sd = 0.f;
    for(int w=0;w<8;w++){
        float pa = 0.f, pd = 0.f;
        #pragma unroll
        for(int cc=0;cc<8;cc++){
            int c = w*8+cc;
            pa += hr[c]*atts[c];
            pd += hr[c]*attd[c];
        }
        sa += pa; sd += pd;
    }
    aS[a] = sa; aD[a] = sd;
}

// layer-0 h: pure gather from hemb/aS/aD
__global__ void k_hx2(const int* __restrict__ xidx, const float* __restrict__ hemb,
                      const float* __restrict__ aS, const float* __restrict__ aD,
                      float* __restrict__ h, float* __restrict__ as_, float* __restrict__ ad_, int n){
    int idx = blockIdx.x*256 + threadIdx.x;
    if(idx >= n*16) return;
    int node = idx>>4, q = idx&15, c0 = q*4;
    int xi = xidx[node];
    *(float4*)(h + (size_t)node*64 + c0) = *(const float4*)(hemb + (size_t)xi*64 + c0);
    if(q==0){ as_[node] = aS[xi]; ad_[node] = aD[xi]; }
}

// ---------------- GAT aggregation: wave per node ----------------

__global__ __launch_bounds__(256) void k_gat(const float* __restrict__ h,
        const float* __restrict__ as_, const float* __restrict__ ad_,
        const float* __restrict__ ae, const int* __restrict__ rowptr,
        const int* __restrict__ csrsrc, const float* __restrict__ bias,
        float* __restrict__ o, int n){
    int node = blockIdx.x*4 + (threadIdx.x>>6);
    if(node >= n) return;
    int lane = threadIdx.x & 63;
    int b = rowptr[node], e = rowptr[node+1];
    float adv = ad_[node];
    float m = -1e30f, d = 0.f, sumae = 0.f;
    float a0=0.f, a1=0.f, a2=0.f, a3=0.f;
    for(int j0=b; j0<e; j0+=64){
        int nj = min(64, e-j0);
        int sj = 0; float aev = 0.f, lg = -1e30f;
        if(lane < nj){
            sj  = csrsrc[j0+lane];
            aev = ae[j0+lane];
            lg  = lrelu(as_[sj] + adv + aev);
        }
        float cm = lg, sa = aev;
        #pragma unroll
        for(int off=32; off; off>>=1){ cm = fmaxf(cm, __shfl_xor(cm,off,64)); sa += __shfl_xor(sa,off,64); }
        sumae += sa;
        float nm = fmaxf(m, cm);
        float w = (lane<nj) ? expf(lg-nm) : 0.f;
        float ws = w;
        #pragma unroll
        for(int off=32; off; off>>=1) ws += __shfl_xor(ws,off,64);
        float scale = (m > -1e29f) ? expf(m-nm) : 0.f;
        d = d*scale + ws;
        a0*=scale; a1*=scale; a2*=scale; a3*=scale;
        int j = 0;
        for(; j+3<nj; j+=4){
            a0 = fmaf(bcastf(w,j+0), h[(size_t)__builtin_amdgcn_readlane(sj,j+0)*64 + lane], a0);
            a1 = fmaf(bcastf(w,j+1), h[(size_t)__builtin_amdgcn_readlane(sj,j+1)*64 + lane], a1);
            a2 = fmaf(bcastf(w,j+2), h[(size_t)__builtin_amdgcn_readlane(sj,j+2)*64 + lane], a2);
            a3 = fmaf(bcastf(w,j+3), h[(size_t)__builtin_amdgcn_readlane(sj,j+3)*64 + lane], a3);
        }
        for(; j<nj; j++)
            a0 = fmaf(bcastf(w,j), h[(size_t)__builtin_amdgcn_readlane(sj,j)*64 + lane], a0);
        m = nm;
    }
    int deg = e - b;
    float ael = sumae / fmaxf((float)deg, 1.f);
    float ls = lrelu(as_[node] + adv + ael);
    float nm = fmaxf(m, ls);
    float scale = (m > -1e29f) ? expf(m-nm) : 0.f;
    float wl = expf(ls-nm);
    d = d*scale + wl;
    float acc = (a0+a1)+(a2+a3);
    acc = acc*scale + wl*h[(size_t)node*64 + lane];
    o[(size_t)node*64 + lane] = acc/d + bias[lane];
}

// ---------------- dense: MLP3 + JKN + fused next-layer h via Wcomb ----------------

__global__ __launch_bounds__(512) void k_dense(
    const float* __restrict__ o,
    const float* __restrict__ W1, const float* __restrict__ b1,
    const float* __restrict__ W2, const float* __restrict__ b2,
    const float* __restrict__ W3, const float* __restrict__ b3,
    float* __restrict__ bestF, float* __restrict__ bestMs, int layer,
    const float* __restrict__ Wc, const float* __restrict__ bc,
    const float* __restrict__ atts, const float* __restrict__ attd,
    float* __restrict__ hn, float* __restrict__ asn, float* __restrict__ adn_,
    const float* __restrict__ A, const float* __restrict__ g1b1,
    const float* __restrict__ w2, const float* __restrict__ g1b2,
    const float* __restrict__ B, const float* __restrict__ g2b1,
    const float* __restrict__ C, const float* __restrict__ g2b2,
    float* __restrict__ h1, float* __restrict__ h2,
    int n, int last)
{
    __shared__ float o_s[64][65];   // o tile -> t2 -> staging
    __shared__ float xs[64][129];   // t1 (cols 0..63) -> x' tile / feature tile
    __shared__ float redA[8][64], redB[8][64];
    __shared__ unsigned char updf[64];
    int base = blockIdx.x*64;
    int t = threadIdx.x, lane = t & 63;
    int wid = __builtin_amdgcn_readfirstlane(t >> 6);

    {   // stage o tile (coalesced)
        int r = t>>3, c0 = (t&7)*8;
        if(base + r < n){
            const float4* srcp = (const float4*)(o + (size_t)(base+r)*64 + c0);
            float4 v0 = srcp[0], v1 = srcp[1];
            o_s[r][c0+0]=v0.x; o_s[r][c0+1]=v0.y; o_s[r][c0+2]=v0.z; o_s[r][c0+3]=v0.w;
            o_s[r][c0+4]=v1.x; o_s[r][c0+5]=v1.y; o_s[r][c0+6]=v1.z; o_s[r][c0+7]=v1.w;
        } else {
            #pragma unroll
            for(int q=0;q<8;q++) o_s[r][c0+q] = 0.f;
        }
    }
    __syncthreads();

    // ---- B: t1 = relu(o @ W1 + b1) -> xs cols 0..63
    {
        int cb = wid*8;
        float acc[8];
        #pragma unroll
        for(int cc=0;cc<8;cc++) acc[cc] = b1[cb+cc];
        for(int k=0;k<64;k++){
            float ov = o_s[lane][k];
            #pragma unroll
            for(int cc=0;cc<8;cc++) acc[cc] = fmaf(ov, W1[k*64 + cb + cc], acc[cc]);
        }
        #pragma unroll
        for(int cc=0;cc<8;cc++) xs[lane][cb+cc] = fmaxf(acc[cc], 0.f);
    }
    __syncthreads();

    // ---- C: t2 = relu(t1 @ W2 + b2) -> o_s (reuse)
    {
        int cb = wid*8;
        float acc[8];
        #pragma unroll
        for(int cc=0;cc<8;cc++) acc[cc] = b2[cb+cc];
        for(int k=0;k<64;k++){
            float tv = xs[lane][k];
            #pragma unroll
            for(int cc=0;cc<8;cc++) acc[cc] = fmaf(tv, W2[k*64 + cb + cc], acc[cc]);
        }
        __syncthreads();
        #pragma unroll
        for(int cc=0;cc<8;cc++) o_s[lane][cb+cc] = fmaxf(acc[cc], 0.f);
    }
    __syncthreads();

    // ---- D: x' = t2 @ W3 + b3 (128 out, 16/lane) -> xs; ms partial
    {
        int cb = wid*16;
        float acc[16];
        #pragma unroll
        for(int cc=0;cc<16;cc++) acc[cc] = b3[cb+cc];
        for(int k=0;k<64;k++){
            float tv = o_s[lane][k];
            #pragma unroll
            for(int cc=0;cc<16;cc++) acc[cc] = fmaf(tv, W3[k*128 + cb + cc], acc[cc]);
        }
        float ms = 0.f;
        #pragma unroll
        for(int cc=0;cc<16;cc++){ xs[lane][cb+cc] = acc[cc]; ms += acc[cc]*acc[cc]; }
        redA[wid][lane] = ms;
    }
    __syncthreads();

    // ---- JKN decision
    if(t < 64){
        int node = base + t; bool u = false;
        if(node < n){
            float ms = 0.f;
            #pragma unroll
            for(int w=0;w<8;w++) ms += redA[w][t];
            u = (layer==0) || (ms > bestMs[node]);
            if(u) bestMs[node] = ms;
        }
        updf[t] = u ? 1 : 0;
    }
    __syncthreads();

    if(!last){
        {   // conditional bestF row copy
            int r = t>>3, c0 = (t&7)*16;
            if(updf[r] && base + r < n){
                float* dst = bestF + (size_t)(base+r)*128 + c0;
                #pragma unroll
                for(int q=0;q<16;q++) dst[q] = xs[r][c0+q];
            }
        }
        // ---- F (fused): h_next = t2 @ Wcomb + bcomb (k=64, reads o_s) + a_s/a_d
        {
            int cb = wid*8;
            float acc[8];
            #pragma unroll
            for(int cc=0;cc<8;cc++) acc[cc] = bc[cb+cc];
            for(int k=0;k<64;k++){
                float tv = o_s[lane][k];
                #pragma unroll
                for(int cc=0;cc<8;cc++) acc[cc] = fmaf(tv, Wc[k*64 + cb + cc], acc[cc]);
            }
            float pa=0.f, pd=0.f;
            #pragma unroll
            for(int cc=0;cc<8;cc++){
                pa += acc[cc]*atts[cb+cc];
                pd += acc[cc]*attd[cb+cc];
            }
            redA[wid][lane]=pa; redB[wid][lane]=pd;
            __syncthreads();          // all waves done READING o_s (t2)
            #pragma unroll
            for(int cc=0;cc<8;cc++) o_s[lane][cb+cc] = acc[cc];
        }
        __syncthreads();
        {
            int r = t>>3, c0 = (t&7)*8;
            if(base + r < n){
                float* dst = hn + (size_t)(base+r)*64 + c0;
                #pragma unroll
                for(int q=0;q<8;q++) dst[q] = o_s[r][c0+q];
            }
        }
        if(t < 64 && base + t < n){
            float sa=0.f, sd=0.f;
            #pragma unroll
            for(int w=0;w<8;w++){ sa += redA[w][t]; sd += redB[w][t]; }
            asn[base+t] = sa; adn_[base+t] = sd;
        }
        return;
    }

    // ================= last layer: fused pooling GEMMs =================
    {   // build feature tile: non-updated rows load old bestF
        int r = t>>3, c0 = (t&7)*16;
        if(!updf[r] && base + r < n){
            const float4* srcp = (const float4*)(bestF + (size_t)(base+r)*128 + c0);
            #pragma unroll
            for(int q=0;q<4;q++){
                float4 v = srcp[q];
                xs[r][c0+q*4+0]=v.x; xs[r][c0+q*4+1]=v.y; xs[r][c0+q*4+2]=v.z; xs[r][c0+q*4+3]=v.w;
            }
        }
    }
    __syncthreads();
    if(wid < 4){      // p1 = relu(F@A+b1); partial h1 = dot(p1, w2)
        int cb = wid*16;
        float acc[16];
        #pragma unroll
        for(int cc=0;cc<16;cc++) acc[cc] = g1b1[cb+cc];
        for(int k=0;k<128;k++){
            float fv = xs[lane][k];
            #pragma unroll
            for(int cc=0;cc<16;cc++) acc[cc] = fmaf(fv, A[k*64 + cb + cc], acc[cc]);
        }
        float pp = 0.f;
        #pragma unroll
        for(int cc=0;cc<16;cc++) pp += fmaxf(acc[cc],0.f)*w2[cb+cc];
        redA[wid][lane] = pp;
    } else {          // p2 = relu(F@B+b1') -> ts (o_s)
        int cb = (wid-4)*16;
        float acc[16];
        #pragma unroll
        for(int cc=0;cc<16;cc++) acc[cc] = g2b1[cb+cc];
        for(int k=0;k<128;k++){
            float fv = xs[lane][k];
            #pragma unroll
            for(int cc=0;cc<16;cc++) acc[cc] = fmaf(fv, B[k*64 + cb + cc], acc[cc]);
        }
        #pragma unroll
        for(int cc=0;cc<16;cc++) o_s[lane][cb+cc] = fmaxf(acc[cc],0.f);
    }
    __syncthreads();
    if(t < 64 && base + t < n)
        h1[base+t] = redA[0][t]+redA[1][t]+redA[2][t]+redA[3][t] + g1b2[0];
    // h2 = ts @ C + b (128 out, 16/lane) -> xs
    {
        int cb = wid*16;
        float acc[16];
        #pragma unroll
        for(int cc=0;cc<16;cc++) acc[cc] = g2b2[cb+cc];
        for(int k=0;k<64;k++){
            float tv = o_s[lane][k];
            #pragma unroll
            for(int cc=0;cc<16;cc++) acc[cc] = fmaf(tv, C[k*128 + cb + cc], acc[cc]);
        }
        __syncthreads();
        #pragma unroll
        for(int cc=0;cc<16;cc++) xs[lane][cb+cc] = acc[cc];
    }
    __syncthreads();
    {
        int r = t>>3, c0 = (t&7)*16;
        if(base + r < n){
            float* dst = h2 + (size_t)(base+r)*128 + c0;
            #pragma unroll
            for(int q=0;q<16;q++) dst[q] = xs[r][c0+q];
        }
    }
}

// ---------------- pooling softmax + per-graph prediction MLP ----------------

__global__ __launch_bounds__(128) void k_pool2(const float* __restrict__ h1, const float* __restrict__ h2,
                      float* __restrict__ wbuf,
                      const float* __restrict__ pW1, const float* __restrict__ pb1,
                      const float* __restrict__ pW2, const float* __restrict__ pb2,
                      const float* __restrict__ pW3, const float* __restrict__ pb3,
                      float* __restrict__ out, int n, int G){
    __shared__ float sh[128];
    __shared__ float hgrow[128];
    int g = blockIdx.x, tid = threadIdx.x;
    int start = (g*n + G-1)/G, end = ((g+1)*n + G-1)/G;
    float lm = -1e30f;
    for(int i=start+tid; i<end; i+=128) lm = fmaxf(lm, h1[i]);
    sh[tid]=lm; __syncthreads();
    for(int off=64; off; off>>=1){ if(tid<off) sh[tid]=fmaxf(sh[tid],sh[tid+off]); __syncthreads(); }
    float m = sh[0]; __syncthreads();
    float lsum = 0.f;
    for(int i=start+tid; i<end; i+=128){ float w = expf(h1[i]-m); wbuf[i]=w; lsum+=w; }
    sh[tid]=lsum; __syncthreads();
    for(int off=64; off; off>>=1){ if(tid<off) sh[tid]+=sh[tid+off]; __syncthreads(); }
    float denom = sh[0];
    float a0=0.f,a1=0.f,a2=0.f,a3=0.f;
    int i = start;
    for(; i+3<end; i+=4){
        a0 = fmaf(wbuf[i+0], h2[(size_t)(i+0)*128 + tid], a0);
        a1 = fmaf(wbuf[i+1], h2[(size_t)(i+1)*128 + tid], a1);
        a2 = fmaf(wbuf[i+2], h2[(size_t)(i+2)*128 + tid], a2);
        a3 = fmaf(wbuf[i+3], h2[(size_t)(i+3)*128 + tid], a3);
    }
    for(; i<end; i++) a0 = fmaf(wbuf[i], h2[(size_t)i*128 + tid], a0);
    float acc = (a0+a1)+(a2+a3);
    hgrow[tid] = acc/denom/(float)(end-start);
    __syncthreads();
    if(tid < 64){
        float t1v = pb1[tid];
        for(int k=0;k<128;k++) t1v = fmaf(hgrow[k], pW1[k*64+tid], t1v);
        t1v = fmaxf(t1v, 0.f);
        float t2v = pb2[tid];
        for(int k=0;k<64;k++) t2v = fmaf(__shfl(t1v,k,64), pW2[k*64+tid], t2v);
        t2v = fmaxf(t2v, 0.f);
        float s = t2v * pW3[tid];
        #pragma unroll
        for(int off=32; off; off>>=1) s += __shfl_xor(s,off,64);
        if(tid==0) out[g] = s + pb3[0];
    }
}

extern "C" void kernel_launch(void* const* d_in, const int* in_sizes, int n_in,
                              void* d_out, int out_size, void* d_ws, size_t ws_size,
                              hipStream_t stream){
    const int*   x_idx   = (const int*)  d_in[0];
    const int*   eindex  = (const int*)  d_in[1];
    const int*   eattr   = (const int*)  d_in[2];
    const float* emb     = (const float*)d_in[4];
    const float* conv_W  = (const float*)d_in[5];
    const float* conv_We = (const float*)d_in[6];
    const float* att_src = (const float*)d_in[7];
    const float* att_dst = (const float*)d_in[8];
    const float* att_edg = (const float*)d_in[9];
    const float* conv_b  = (const float*)d_in[10];
    const float* mW1 = (const float*)d_in[11]; const float* mb1 = (const float*)d_in[12];
    const float* mW2 = (const float*)d_in[13]; const float* mb2 = (const float*)d_in[14];
    const float* mW3 = (const float*)d_in[15]; const float* mb3 = (const float*)d_in[16];
    const float* g1W1= (const float*)d_in[17]; const float* g1b1= (const float*)d_in[18];
    const float* g1W2= (const float*)d_in[19]; const float* g1b2= (const float*)d_in[20];
    const float* g2W1= (const float*)d_in[21]; const float* g2b1= (const float*)d_in[22];
    const float* g2W2= (const float*)d_in[23]; const float* g2b2= (const float*)d_in[24];
    const float* pW1 = (const float*)d_in[25]; const float* pb1 = (const float*)d_in[26];
    const float* pW2 = (const float*)d_in[27]; const float* pb2 = (const float*)d_in[28];
    const float* pW3 = (const float*)d_in[29]; const float* pb3 = (const float*)d_in[30];

    const int N = in_sizes[0];
    const int E = in_sizes[2];
    const int G = out_size;
    const int* src = eindex;
    const int* dst = eindex + E;
    const int NT = (N + 63) / 64;
    const int NW = (N + 3) / 4;

    char* p = (char*)d_ws;
    auto alloc = [&](size_t bytes)->void*{ void* r = (void*)p; p += (bytes + 255) & ~(size_t)255; return r; };
    float* h      = (float*)alloc((size_t)N*64*4);
    float* o      = (float*)alloc((size_t)N*64*4);
    float* bestF  = (float*)alloc((size_t)N*128*4);
    float* h2buf  = (float*)alloc((size_t)N*128*4);
    float* bestMs = (float*)alloc((size_t)N*4);
    float* as_    = (float*)alloc((size_t)N*4);
    float* ad_    = (float*)alloc((size_t)N*4);
    float* ae     = (float*)alloc((size_t)6*E*4);
    float* Tbuf   = (float*)alloc(6*128*4);
    float* h1     = (float*)alloc((size_t)N*4);
    float* Wcomb  = (float*)alloc(5*4096*4);
    float* bcomb  = (float*)alloc(5*64*4);
    float* hemb   = (float*)alloc(128*64*4);
    float* aS     = (float*)alloc(128*4);
    float* aD     = (float*)alloc(128*4);
    int*   cnt    = (int*)  alloc((size_t)N*4);
    int*   cnt2   = (int*)  alloc((size_t)N*4);
    int*   rowptr = (int*)  alloc((size_t)(N+1)*4);
    int*   eid    = (int*)  alloc((size_t)E*4);
    int*   csrsrc = (int*)  alloc((size_t)E*4);

    hipMemsetAsync(cnt,  0, (size_t)N*4, stream);
    hipMemsetAsync(cnt2, 0, (size_t)N*4, stream);

    k_count<<<(E+255)/256, 256, 0, stream>>>(dst, cnt, E);
    k_scan<<<1, 1024, 0, stream>>>(cnt, rowptr, N);
    k_scatter<<<(E+255)/256, 256, 0, stream>>>(dst, rowptr, cnt2, eid, E);
    k_sortb<<<NW, 256, 0, stream>>>(rowptr, eid, N);
    k_table<<<1, 768, 0, stream>>>(conv_We, att_edg, emb, Tbuf);
    k_ae2<<<(E+255)/256, 256, 0, stream>>>(eid, src, eattr, Tbuf, csrsrc, ae, E);
    k_wcomb<<<5, 256, 0, stream>>>(mW3, conv_W, mb3, Wcomb, bcomb);
    k_hemb<<<1, 512, 0, stream>>>(emb, conv_W, hemb);
    k_aemb<<<1, 128, 0, stream>>>(hemb, att_src, att_dst, aS, aD);
    k_hx2<<<(N*16+255)/256, 256, 0, stream>>>(x_idx, hemb, aS, aD, h, as_, ad_, N);

    for(int l=0; l<6; l++){
        int last = (l==5) ? 1 : 0;
        const float* Wc   = last ? Wcomb : Wcomb + (size_t)l*4096;
        const float* bcp  = last ? bcomb : bcomb + (size_t)l*64;
        const float* atsn = last ? att_src : att_src + (l+1)*64;
        const float* atdn = last ? att_dst : att_dst + (l+1)*64;
        k_gat<<<NW, 256, 0, stream>>>(h, as_, ad_, ae + (size_t)l*E, rowptr, csrsrc, conv_b + l*64, o, N);
        k_dense<<<NT, 512, 0, stream>>>(o,
            mW1 + (size_t)l*4096, mb1 + l*64, mW2 + (size_t)l*4096, mb2 + l*64,
            mW3 + (size_t)l*8192, mb3 + l*128,
            bestF, bestMs, l,
            Wc, bcp, atsn, atdn,
            h, as_, ad_,
            g1W1, g1b1, g1W2, g1b2, g2W1, g2b1, g2W2, g2b2,
            h1, h2buf,
            N, last);
    }

    k_pool2<<<G, 128, 0, stream>>>(h1, h2buf, bestMs,
            pW1, pb1, pW2, pb2, pW3, pb3, (float*)d_out, N, G);
}

// Round 14
// 484.807 us; speedup vs baseline: 1.1458x; 1.1458x over previous
//
#include <hip/hip_runtime.h>
#include <math.h>

__device__ __forceinline__ float lrelu(float x){ return x > 0.0f ? x : 0.2f*x; }
__device__ __forceinline__ float bcastf(float v, int l){
    return __int_as_float(__builtin_amdgcn_readlane(__float_as_int(v), l));
}

// ---------------- precompute ----------------

__global__ void k_count(const int* __restrict__ dst, int* __restrict__ cnt, int E){
    int e = blockIdx.x*256 + threadIdx.x;
    if(e < E) atomicAdd(&cnt[dst[e]], 1);
}

__global__ __launch_bounds__(1024) void k_scan(const int* __restrict__ cnt, int* __restrict__ rowptr, int n){
    __shared__ int ws[16];
    __shared__ int carrysh;
    int t = threadIdx.x, lane = t & 63, wv = t >> 6;
    if(t==0){ carrysh = 0; rowptr[0] = 0; }
    __syncthreads();
    for(int base=0; base<n; base+=1024){
        int i = base + t;
        int v = (i<n) ? cnt[i] : 0;
        int s = v;
        #pragma unroll
        for(int off=1; off<64; off<<=1){ int u = __shfl_up(s, off, 64); if(lane>=off) s += u; }
        if(lane==63) ws[wv] = s;
        __syncthreads();
        if(t < 16){
            int u = ws[t];
            #pragma unroll
            for(int off=1; off<16; off<<=1){ int u2 = __shfl_up(u, off, 16); if(t>=off) u += u2; }
            ws[t] = u;
        }
        __syncthreads();
        int carry = carrysh;
        int wbase = wv ? ws[wv-1] : 0;
        if(i<n) rowptr[i+1] = carry + wbase + s;
        int total = ws[15];
        __syncthreads();
        if(t==0) carrysh = carry + total;
        __syncthreads();
    }
}

__global__ void k_scatter(const int* __restrict__ dst, const int* __restrict__ rowptr,
                          int* __restrict__ cnt2, int* __restrict__ eid, int E){
    int e = blockIdx.x*256 + threadIdx.x;
    if(e >= E) return;
    int d = dst[e];
    int p = rowptr[d] + atomicAdd(&cnt2[d], 1);
    eid[p] = e;
}

__global__ __launch_bounds__(256) void k_sortb(const int* __restrict__ rowptr, int* __restrict__ eid, int n){
    int node = blockIdx.x*4 + (threadIdx.x>>6);
    if(node >= n) return;
    int lane = threadIdx.x & 63;
    int b = rowptr[node], e = rowptr[node+1];
    int nj = e - b;
    if(nj <= 1) return;
    if(nj <= 64){
        int v = (lane < nj) ? eid[b+lane] : 0x7fffffff;
        for(int k=2; k<=64; k<<=1){
            for(int j=k>>1; j>0; j>>=1){
                int vv = __shfl_xor(v, j, 64);
                bool up = ((lane & k) == 0);
                bool lower = ((lane & j) == 0);
                int mn = min(v,vv), mx = max(v,vv);
                v = (lower == up) ? mn : mx;
            }
        }
        if(lane < nj) eid[b+lane] = v;
    } else if(lane == 0){
        for(int i=b+1; i<e; i++){
            int key = eid[i]; int j = i-1;
            while(j>=b && eid[j] > key){ eid[j+1] = eid[j]; j--; }
            eid[j+1] = key;
        }
    }
}

// T[l][a] = emb[a] . wvec[l]
__global__ __launch_bounds__(768) void k_table(const float* __restrict__ We, const float* __restrict__ atte,
                                               const float* __restrict__ emb, float* __restrict__ T){
    __shared__ float wv[768];
    int t = threadIdx.x;
    {
        int l = t>>7, k = t&127;
        const float* w = We + ((size_t)l*128 + k)*64;
        const float* a = atte + l*64;
        float s = 0.f;
        #pragma unroll 8
        for(int c=0;c<64;c++) s += w[c]*a[c];
        wv[t] = s;
    }
    __syncthreads();
    int l = t>>7, a = t&127;
    const float4* er = (const float4*)(emb + (size_t)a*128);
    const float* w = wv + l*128;
    float acc = 0.f;
    for(int k=0;k<32;k++){
        float4 v = er[k];
        acc += v.x*w[k*4+0] + v.y*w[k*4+1] + v.z*w[k*4+2] + v.w*w[k*4+3];
    }
    T[l*128 + a] = acc;
}

// fill csrsrc + ae[l][p] by table lookup (pure gather)
__global__ __launch_bounds__(256) void k_ae2(const int* __restrict__ eid, const int* __restrict__ src,
                     const int* __restrict__ eattr, const float* __restrict__ T,
                     int* __restrict__ csrsrc, float* __restrict__ ae, int E){
    __shared__ float Tl[768];
    for(int i=threadIdx.x; i<768; i+=256) Tl[i] = T[i];
    __syncthreads();
    int p = blockIdx.x*256 + threadIdx.x;
    if(p >= E) return;
    int e = eid[p];
    csrsrc[p] = src[e];
    int a = eattr[e];
    #pragma unroll
    for(int l=0;l<6;l++) ae[(size_t)l*E + p] = Tl[l*128 + a];
}

// Wcomb[l] = W3[l] @ Wn[l+1]; bcomb[l] = b3[l] @ Wn[l+1]
// 325 blocks x 64 threads: block = (l, output row r) with r==64 -> bias row.
// Same sequential-j accumulation order as before (validated absmax 0.0).
__global__ __launch_bounds__(64) void k_wcomb(const float* __restrict__ W3all, const float* __restrict__ Wnall,
                                              const float* __restrict__ b3all,
                                              float* __restrict__ Wcomb, float* __restrict__ bcomb){
    int bid = blockIdx.x;
    int l = bid / 65, r = bid % 65;
    const float* Wn = Wnall + (size_t)(l+1)*8192;
    int c = threadIdx.x;
    if(r < 64){
        const float* w3r = W3all + (size_t)l*8192 + r*128;
        float s = 0.f;
        for(int j=0;j<128;j++) s += w3r[j]*Wn[j*64+c];
        Wcomb[l*4096 + r*64 + c] = s;
    } else {
        const float* b3 = b3all + l*128;
        float s = 0.f;
        for(int j=0;j<128;j++) s += b3[j]*Wn[j*64+c];
        bcomb[l*64+c] = s;
    }
}

// hemb[a][c] = emb[a] @ conv_W[0]  — sequential-k order identical to old k_hx (bit-exact)
__global__ __launch_bounds__(512) void k_hemb(const float* __restrict__ emb, const float* __restrict__ W0,
                                              float* __restrict__ hemb){
    int t = threadIdx.x;
    int a = t>>2, c0 = (t&3)*16;
    const float* er = emb + (size_t)a*128;
    float acc[16];
    #pragma unroll
    for(int cc=0;cc<16;cc++) acc[cc] = 0.f;
    for(int k=0;k<128;k++){
        float xv = er[k];
        #pragma unroll
        for(int cc=0;cc<16;cc++) acc[cc] = fmaf(xv, W0[k*64 + c0 + cc], acc[cc]);
    }
    #pragma unroll
    for(int cc=0;cc<16;cc++) hemb[a*64 + c0 + cc] = acc[cc];
}

// aS[a]/aD[a] with the old k_hx's 8-chunk reduction order (bit-exact)
__global__ __launch_bounds__(128) void k_aemb(const float* __restrict__ hemb,
                                              const float* __restrict__ atts, const float* __restrict__ attd,
                                              float* __restrict__ aS, float* __restrict__ aD){
    int a = threadIdx.x;
    const float* hr = hemb + a*64;
    float sa = 0.f, sd = 0.f;
    for(int w=0;w<8;w++){
        float pa = 0.f, pd = 0.f;
        #pragma unroll
        for(int cc=0;cc<8;cc++){
            int c = w*8+cc;
            pa += hr[c]*atts[c];
            pd += hr[c]*attd[c];
        }
        sa += pa; sd += pd;
    }
    aS[a] = sa; aD[a] = sd;
}

// layer-0 h: pure gather from hemb/aS/aD
__global__ void k_hx2(const int* __restrict__ xidx, const float* __restrict__ hemb,
                      const float* __restrict__ aS, const float* __restrict__ aD,
                      float* __restrict__ h, float* __restrict__ as_, float* __restrict__ ad_, int n){
    int idx = blockIdx.x*256 + threadIdx.x;
    if(idx >= n*16) return;
    int node = idx>>4, q = idx&15, c0 = q*4;
    int xi = xidx[node];
    *(float4*)(h + (size_t)node*64 + c0) = *(const float4*)(hemb + (size_t)xi*64 + c0);
    if(q==0){ as_[node] = aS[xi]; ad_[node] = aD[xi]; }
}

// ---------------- GAT aggregation: wave per node ----------------

__global__ __launch_bounds__(256) void k_gat(const float* __restrict__ h,
        const float* __restrict__ as_, const float* __restrict__ ad_,
        const float* __restrict__ ae, const int* __restrict__ rowptr,
        const int* __restrict__ csrsrc, const float* __restrict__ bias,
        float* __restrict__ o, int n){
    int node = blockIdx.x*4 + (threadIdx.x>>6);
    if(node >= n) return;
    int lane = threadIdx.x & 63;
    int b = rowptr[node], e = rowptr[node+1];
    float adv = ad_[node];
    float m = -1e30f, d = 0.f, sumae = 0.f;
    float a0=0.f, a1=0.f, a2=0.f, a3=0.f;
    for(int j0=b; j0<e; j0+=64){
        int nj = min(64, e-j0);
        int sj = 0; float aev = 0.f, lg = -1e30f;
        if(lane < nj){
            sj  = csrsrc[j0+lane];
            aev = ae[j0+lane];
            lg  = lrelu(as_[sj] + adv + aev);
        }
        float cm = lg, sa = aev;
        #pragma unroll
        for(int off=32; off; off>>=1){ cm = fmaxf(cm, __shfl_xor(cm,off,64)); sa += __shfl_xor(sa,off,64); }
        sumae += sa;
        float nm = fmaxf(m, cm);
        float w = (lane<nj) ? expf(lg-nm) : 0.f;
        float ws = w;
        #pragma unroll
        for(int off=32; off; off>>=1) ws += __shfl_xor(ws,off,64);
        float scale = (m > -1e29f) ? expf(m-nm) : 0.f;
        d = d*scale + ws;
        a0*=scale; a1*=scale; a2*=scale; a3*=scale;
        int j = 0;
        for(; j+3<nj; j+=4){
            a0 = fmaf(bcastf(w,j+0), h[(size_t)__builtin_amdgcn_readlane(sj,j+0)*64 + lane], a0);
            a1 = fmaf(bcastf(w,j+1), h[(size_t)__builtin_amdgcn_readlane(sj,j+1)*64 + lane], a1);
            a2 = fmaf(bcastf(w,j+2), h[(size_t)__builtin_amdgcn_readlane(sj,j+2)*64 + lane], a2);
            a3 = fmaf(bcastf(w,j+3), h[(size_t)__builtin_amdgcn_readlane(sj,j+3)*64 + lane], a3);
        }
        for(; j<nj; j++)
            a0 = fmaf(bcastf(w,j), h[(size_t)__builtin_amdgcn_readlane(sj,j)*64 + lane], a0);
        m = nm;
    }
    int deg = e - b;
    float ael = sumae / fmaxf((float)deg, 1.f);
    float ls = lrelu(as_[node] + adv + ael);
    float nm = fmaxf(m, ls);
    float scale = (m > -1e29f) ? expf(m-nm) : 0.f;
    float wl = expf(ls-nm);
    d = d*scale + wl;
    float acc = (a0+a1)+(a2+a3);
    acc = acc*scale + wl*h[(size_t)node*64 + lane];
    o[(size_t)node*64 + lane] = acc/d + bias[lane];
}

// ---------------- dense: MLP3 + JKN + fused next-layer h via Wcomb ----------------

__global__ __launch_bounds__(512) void k_dense(
    const float* __restrict__ o,
    const float* __restrict__ W1, const float* __restrict__ b1,
    const float* __restrict__ W2, const float* __restrict__ b2,
    const float* __restrict__ W3, const float* __restrict__ b3,
    float* __restrict__ bestF, float* __restrict__ bestMs, int layer,
    const float* __restrict__ Wc, const float* __restrict__ bc,
    const float* __restrict__ atts, const float* __restrict__ attd,
    float* __restrict__ hn, float* __restrict__ asn, float* __restrict__ adn_,
    const float* __restrict__ A, const float* __restrict__ g1b1,
    const float* __restrict__ w2, const float* __restrict__ g1b2,
    const float* __restrict__ B, const float* __restrict__ g2b1,
    const float* __restrict__ C, const float* __restrict__ g2b2,
    float* __restrict__ h1, float* __restrict__ h2,
    int n, int last)
{
    __shared__ float o_s[64][65];   // o tile -> t2 -> staging
    __shared__ float xs[64][129];   // t1 (cols 0..63) -> x' tile / feature tile
    __shared__ float redA[8][64], redB[8][64];
    __shared__ unsigned char updf[64];
    int base = blockIdx.x*64;
    int t = threadIdx.x, lane = t & 63;
    int wid = __builtin_amdgcn_readfirstlane(t >> 6);

    {   // stage o tile (coalesced)
        int r = t>>3, c0 = (t&7)*8;
        if(base + r < n){
            const float4* srcp = (const float4*)(o + (size_t)(base+r)*64 + c0);
            float4 v0 = srcp[0], v1 = srcp[1];
            o_s[r][c0+0]=v0.x; o_s[r][c0+1]=v0.y; o_s[r][c0+2]=v0.z; o_s[r][c0+3]=v0.w;
            o_s[r][c0+4]=v1.x; o_s[r][c0+5]=v1.y; o_s[r][c0+6]=v1.z; o_s[r][c0+7]=v1.w;
        } else {
            #pragma unroll
            for(int q=0;q<8;q++) o_s[r][c0+q] = 0.f;
        }
    }
    __syncthreads();

    // ---- B: t1 = relu(o @ W1 + b1) -> xs cols 0..63
    {
        int cb = wid*8;
        float acc[8];
        #pragma unroll
        for(int cc=0;cc<8;cc++) acc[cc] = b1[cb+cc];
        for(int k=0;k<64;k++){
            float ov = o_s[lane][k];
            #pragma unroll
            for(int cc=0;cc<8;cc++) acc[cc] = fmaf(ov, W1[k*64 + cb + cc], acc[cc]);
        }
        #pragma unroll
        for(int cc=0;cc<8;cc++) xs[lane][cb+cc] = fmaxf(acc[cc], 0.f);
    }
    __syncthreads();

    // ---- C: t2 = relu(t1 @ W2 + b2) -> o_s (reuse)
    {
        int cb = wid*8;
        float acc[8];
        #pragma unroll
        for(int cc=0;cc<8;cc++) acc[cc] = b2[cb+cc];
        for(int k=0;k<64;k++){
            float tv = xs[lane][k];
            #pragma unroll
            for(int cc=0;cc<8;cc++) acc[cc] = fmaf(tv, W2[k*64 + cb + cc], acc[cc]);
        }
        __syncthreads();
        #pragma unroll
        for(int cc=0;cc<8;cc++) o_s[lane][cb+cc] = fmaxf(acc[cc], 0.f);
    }
    __syncthreads();

    // ---- D: x' = t2 @ W3 + b3 (128 out, 16/lane) -> xs; ms partial
    {
        int cb = wid*16;
        float acc[16];
        #pragma unroll
        for(int cc=0;cc<16;cc++) acc[cc] = b3[cb+cc];
        for(int k=0;k<64;k++){
            float tv = o_s[lane][k];
            #pragma unroll
            for(int cc=0;cc<16;cc++) acc[cc] = fmaf(tv, W3[k*128 + cb + cc], acc[cc]);
        }
        float ms = 0.f;
        #pragma unroll
        for(int cc=0;cc<16;cc++){ xs[lane][cb+cc] = acc[cc]; ms += acc[cc]*acc[cc]; }
        redA[wid][lane] = ms;
    }
    __syncthreads();

    // ---- JKN decision
    if(t < 64){
        int node = base + t; bool u = false;
        if(node < n){
            float ms = 0.f;
            #pragma unroll
            for(int w=0;w<8;w++) ms += redA[w][t];
            u = (layer==0) || (ms > bestMs[node]);
            if(u) bestMs[node] = ms;
        }
        updf[t] = u ? 1 : 0;
    }
    __syncthreads();

    if(!last){
        {   // conditional bestF row copy
            int r = t>>3, c0 = (t&7)*16;
            if(updf[r] && base + r < n){
                float* dst = bestF + (size_t)(base+r)*128 + c0;
                #pragma unroll
                for(int q=0;q<16;q++) dst[q] = xs[r][c0+q];
            }
        }
        // ---- F (fused): h_next = t2 @ Wcomb + bcomb (k=64, reads o_s) + a_s/a_d
        {
            int cb = wid*8;
            float acc[8];
            #pragma unroll
            for(int cc=0;cc<8;cc++) acc[cc] = bc[cb+cc];
            for(int k=0;k<64;k++){
                float tv = o_s[lane][k];
                #pragma unroll
                for(int cc=0;cc<8;cc++) acc[cc] = fmaf(tv, Wc[k*64 + cb + cc], acc[cc]);
            }
            float pa=0.f, pd=0.f;
            #pragma unroll
            for(int cc=0;cc<8;cc++){
                pa += acc[cc]*atts[cb+cc];
                pd += acc[cc]*attd[cb+cc];
            }
            redA[wid][lane]=pa; redB[wid][lane]=pd;
            __syncthreads();          // all waves done READING o_s (t2)
            #pragma unroll
            for(int cc=0;cc<8;cc++) o_s[lane][cb+cc] = acc[cc];
        }
        __syncthreads();
        {
            int r = t>>3, c0 = (t&7)*8;
            if(base + r < n){
                float* dst = hn + (size_t)(base+r)*64 + c0;
                #pragma unroll
                for(int q=0;q<8;q++) dst[q] = o_s[r][c0+q];
            }
        }
        if(t < 64 && base + t < n){
            float sa=0.f, sd=0.f;
            #pragma unroll
            for(int w=0;w<8;w++){ sa += redA[w][t]; sd += redB[w][t]; }
            asn[base+t] = sa; adn_[base+t] = sd;
        }
        return;
    }

    // ================= last layer: fused pooling GEMMs =================
    {   // build feature tile: non-updated rows load old bestF
        int r = t>>3, c0 = (t&7)*16;
        if(!updf[r] && base + r < n){
            const float4* srcp = (const float4*)(bestF + (size_t)(base+r)*128 + c0);
            #pragma unroll
            for(int q=0;q<4;q++){
                float4 v = srcp[q];
                xs[r][c0+q*4+0]=v.x; xs[r][c0+q*4+1]=v.y; xs[r][c0+q*4+2]=v.z; xs[r][c0+q*4+3]=v.w;
            }
        }
    }
    __syncthreads();
    if(wid < 4){      // p1 = relu(F@A+b1); partial h1 = dot(p1, w2)
        int cb = wid*16;
        float acc[16];
        #pragma unroll
        for(int cc=0;cc<16;cc++) acc[cc] = g1b1[cb+cc];
        for(int k=0;k<128;k++){
            float fv = xs[lane][k];
            #pragma unroll
            for(int cc=0;cc<16;cc++) acc[cc] = fmaf(fv, A[k*64 + cb + cc], acc[cc]);
        }
        float pp = 0.f;
        #pragma unroll
        for(int cc=0;cc<16;cc++) pp += fmaxf(acc[cc],0.f)*w2[cb+cc];
        redA[wid][lane] = pp;
    } else {          // p2 = relu(F@B+b1') -> ts (o_s)
        int cb = (wid-4)*16;
        float acc[16];
        #pragma unroll
        for(int cc=0;cc<16;cc++) acc[cc] = g2b1[cb+cc];
        for(int k=0;k<128;k++){
            float fv = xs[lane][k];
            #pragma unroll
            for(int cc=0;cc<16;cc++) acc[cc] = fmaf(fv, B[k*64 + cb + cc], acc[cc]);
        }
        #pragma unroll
        for(int cc=0;cc<16;cc++) o_s[lane][cb+cc] = fmaxf(acc[cc],0.f);
    }
    __syncthreads();
    if(t < 64 && base + t < n)
        h1[base+t] = redA[0][t]+redA[1][t]+redA[2][t]+redA[3][t] + g1b2[0];
    // h2 = ts @ C + b (128 out, 16/lane) -> xs
    {
        int cb = wid*16;
        float acc[16];
        #pragma unroll
        for(int cc=0;cc<16;cc++) acc[cc] = g2b2[cb+cc];
        for(int k=0;k<64;k++){
            float tv = o_s[lane][k];
            #pragma unroll
            for(int cc=0;cc<16;cc++) acc[cc] = fmaf(tv, C[k*128 + cb + cc], acc[cc]);
        }
        __syncthreads();
        #pragma unroll
        for(int cc=0;cc<16;cc++) xs[lane][cb+cc] = acc[cc];
    }
    __syncthreads();
    {
        int r = t>>3, c0 = (t&7)*16;
        if(base + r < n){
            float* dst = h2 + (size_t)(base+r)*128 + c0;
            #pragma unroll
            for(int q=0;q<16;q++) dst[q] = xs[r][c0+q];
        }
    }
}

// ---------------- pooling softmax + per-graph prediction MLP ----------------

__global__ __launch_bounds__(128) void k_pool2(const float* __restrict__ h1, const float* __restrict__ h2,
                      float* __restrict__ wbuf,
                      const float* __restrict__ pW1, const float* __restrict__ pb1,
                      const float* __restrict__ pW2, const float* __restrict__ pb2,
                      const float* __restrict__ pW3, const float* __restrict__ pb3,
                      float* __restrict__ out, int n, int G){
    __shared__ float sh[128];
    __shared__ float hgrow[128];
    int g = blockIdx.x, tid = threadIdx.x;
    int start = (g*n + G-1)/G, end = ((g+1)*n + G-1)/G;
    float lm = -1e30f;
    for(int i=start+tid; i<end; i+=128) lm = fmaxf(lm, h1[i]);
    sh[tid]=lm; __syncthreads();
    for(int off=64; off; off>>=1){ if(tid<off) sh[tid]=fmaxf(sh[tid],sh[tid+off]); __syncthreads(); }
    float m = sh[0]; __syncthreads();
    float lsum = 0.f;
    for(int i=start+tid; i<end; i+=128){ float w = expf(h1[i]-m); wbuf[i]=w; lsum+=w; }
    sh[tid]=lsum; __syncthreads();
    for(int off=64; off; off>>=1){ if(tid<off) sh[tid]+=sh[tid+off]; __syncthreads(); }
    float denom = sh[0];
    float a0=0.f,a1=0.f,a2=0.f,a3=0.f;
    int i = start;
    for(; i+3<end; i+=4){
        a0 = fmaf(wbuf[i+0], h2[(size_t)(i+0)*128 + tid], a0);
        a1 = fmaf(wbuf[i+1], h2[(size_t)(i+1)*128 + tid], a1);
        a2 = fmaf(wbuf[i+2], h2[(size_t)(i+2)*128 + tid], a2);
        a3 = fmaf(wbuf[i+3], h2[(size_t)(i+3)*128 + tid], a3);
    }
    for(; i<end; i++) a0 = fmaf(wbuf[i], h2[(size_t)i*128 + tid], a0);
    float acc = (a0+a1)+(a2+a3);
    hgrow[tid] = acc/denom/(float)(end-start);
    __syncthreads();
    if(tid < 64){
        float t1v = pb1[tid];
        for(int k=0;k<128;k++) t1v = fmaf(hgrow[k], pW1[k*64+tid], t1v);
        t1v = fmaxf(t1v, 0.f);
        float t2v = pb2[tid];
        for(int k=0;k<64;k++) t2v = fmaf(__shfl(t1v,k,64), pW2[k*64+tid], t2v);
        t2v = fmaxf(t2v, 0.f);
        float s = t2v * pW3[tid];
        #pragma unroll
        for(int off=32; off; off>>=1) s += __shfl_xor(s,off,64);
        if(tid==0) out[g] = s + pb3[0];
    }
}

extern "C" void kernel_launch(void* const* d_in, const int* in_sizes, int n_in,
                              void* d_out, int out_size, void* d_ws, size_t ws_size,
                              hipStream_t stream){
    const int*   x_idx   = (const int*)  d_in[0];
    const int*   eindex  = (const int*)  d_in[1];
    const int*   eattr   = (const int*)  d_in[2];
    const float* emb     = (const float*)d_in[4];
    const float* conv_W  = (const float*)d_in[5];
    const float* conv_We = (const float*)d_in[6];
    const float* att_src = (const float*)d_in[7];
    const float* att_dst = (const float*)d_in[8];
    const float* att_edg = (const float*)d_in[9];
    const float* conv_b  = (const float*)d_in[10];
    const float* mW1 = (const float*)d_in[11]; const float* mb1 = (const float*)d_in[12];
    const float* mW2 = (const float*)d_in[13]; const float* mb2 = (const float*)d_in[14];
    const float* mW3 = (const float*)d_in[15]; const float* mb3 = (const float*)d_in[16];
    const float* g1W1= (const float*)d_in[17]; const float* g1b1= (const float*)d_in[18];
    const float* g1W2= (const float*)d_in[19]; const float* g1b2= (const float*)d_in[20];
    const float* g2W1= (const float*)d_in[21]; const float* g2b1= (const float*)d_in[22];
    const float* g2W2= (const float*)d_in[23]; const float* g2b2= (const float*)d_in[24];
    const float* pW1 = (const float*)d_in[25]; const float* pb1 = (const float*)d_in[26];
    const float* pW2 = (const float*)d_in[27]; const float* pb2 = (const float*)d_in[28];
    const float* pW3 = (const float*)d_in[29]; const float* pb3 = (const float*)d_in[30];

    const int N = in_sizes[0];
    const int E = in_sizes[2];
    const int G = out_size;
    const int* src = eindex;
    const int* dst = eindex + E;
    const int NT = (N + 63) / 64;
    const int NW = (N + 3) / 4;

    char* p = (char*)d_ws;
    auto alloc = [&](size_t bytes)->void*{ void* r = (void*)p; p += (bytes + 255) & ~(size_t)255; return r; };
    float* h      = (float*)alloc((size_t)N*64*4);
    float* o      = (float*)alloc((size_t)N*64*4);
    float* bestF  = (float*)alloc((size_t)N*128*4);
    float* h2buf  = (float*)alloc((size_t)N*128*4);
    float* bestMs = (float*)alloc((size_t)N*4);
    float* as_    = (float*)alloc((size_t)N*4);
    float* ad_    = (float*)alloc((size_t)N*4);
    float* ae     = (float*)alloc((size_t)6*E*4);
    float* Tbuf   = (float*)alloc(6*128*4);
    float* h1     = (float*)alloc((size_t)N*4);
    float* Wcomb  = (float*)alloc(5*4096*4);
    float* bcomb  = (float*)alloc(5*64*4);
    float* hemb   = (float*)alloc(128*64*4);
    float* aS     = (float*)alloc(128*4);
    float* aD     = (float*)alloc(128*4);
    int*   cnt    = (int*)  alloc((size_t)N*4);
    int*   cnt2   = (int*)  alloc((size_t)N*4);
    int*   rowptr = (int*)  alloc((size_t)(N+1)*4);
    int*   eid    = (int*)  alloc((size_t)E*4);
    int*   csrsrc = (int*)  alloc((size_t)E*4);

    hipMemsetAsync(cnt,  0, (size_t)N*4, stream);
    hipMemsetAsync(cnt2, 0, (size_t)N*4, stream);

    k_count<<<(E+255)/256, 256, 0, stream>>>(dst, cnt, E);
    k_scan<<<1, 1024, 0, stream>>>(cnt, rowptr, N);
    k_scatter<<<(E+255)/256, 256, 0, stream>>>(dst, rowptr, cnt2, eid, E);
    k_sortb<<<NW, 256, 0, stream>>>(rowptr, eid, N);
    k_table<<<1, 768, 0, stream>>>(conv_We, att_edg, emb, Tbuf);
    k_ae2<<<(E+255)/256, 256, 0, stream>>>(eid, src, eattr, Tbuf, csrsrc, ae, E);
    k_wcomb<<<5*65, 64, 0, stream>>>(mW3, conv_W, mb3, Wcomb, bcomb);
    k_hemb<<<1, 512, 0, stream>>>(emb, conv_W, hemb);
    k_aemb<<<1, 128, 0, stream>>>(hemb, att_src, att_dst, aS, aD);
    k_hx2<<<(N*16+255)/256, 256, 0, stream>>>(x_idx, hemb, aS, aD, h, as_, ad_, N);

    for(int l=0; l<6; l++){
        int last = (l==5) ? 1 : 0;
        const float* Wc   = last ? Wcomb : Wcomb + (size_t)l*4096;
        const float* bcp  = last ? bcomb : bcomb + (size_t)l*64;
        const float* atsn = last ? att_src : att_src + (l+1)*64;
        const float* atdn = last ? att_dst : att_dst + (l+1)*64;
        k_gat<<<NW, 256, 0, stream>>>(h, as_, ad_, ae + (size_t)l*E, rowptr, csrsrc, conv_b + l*64, o, N);
        k_dense<<<NT, 512, 0, stream>>>(o,
            mW1 + (size_t)l*4096, mb1 + l*64, mW2 + (size_t)l*4096, mb2 + l*64,
            mW3 + (size_t)l*8192, mb3 + l*128,
            bestF, bestMs, l,
            Wc, bcp, atsn, atdn,
            h, as_, ad_,
            g1W1, g1b1, g1W2, g1b2, g2W1, g2b1, g2W2, g2b2,
            h1, h2buf,
            N, last);
    }

    k_pool2<<<G, 128, 0, stream>>>(h1, h2buf, bestMs,
            pW1, pb1, pW2, pb2, pW3, pb3, (float*)d_out, N, G);
}

// Round 16
// 430.758 us; speedup vs baseline: 1.2896x; 1.1255x over previous
//
#include <hip/hip_runtime.h>
#include <math.h>

__device__ __forceinline__ float lrelu(float x){ return x > 0.0f ? x : 0.2f*x; }
__device__ __forceinline__ float bcastf(float v, int l){
    return __int_as_float(__builtin_amdgcn_readlane(__float_as_int(v), l));
}

// ---------------- precompute ----------------

__global__ void k_count(const int* __restrict__ dst, int* __restrict__ cnt, int E){
    int e = blockIdx.x*256 + threadIdx.x;
    if(e < E) atomicAdd(&cnt[dst[e]], 1);
}

__global__ __launch_bounds__(1024) void k_scan(const int* __restrict__ cnt, int* __restrict__ rowptr, int n){
    __shared__ int ws[16];
    __shared__ int carrysh;
    int t = threadIdx.x, lane = t & 63, wv = t >> 6;
    if(t==0){ carrysh = 0; rowptr[0] = 0; }
    __syncthreads();
    for(int base=0; base<n; base+=1024){
        int i = base + t;
        int v = (i<n) ? cnt[i] : 0;
        int s = v;
        #pragma unroll
        for(int off=1; off<64; off<<=1){ int u = __shfl_up(s, off, 64); if(lane>=off) s += u; }
        if(lane==63) ws[wv] = s;
        __syncthreads();
        if(t < 16){
            int u = ws[t];
            #pragma unroll
            for(int off=1; off<16; off<<=1){ int u2 = __shfl_up(u, off, 16); if(t>=off) u += u2; }
            ws[t] = u;
        }
        __syncthreads();
        int carry = carrysh;
        int wbase = wv ? ws[wv-1] : 0;
        if(i<n) rowptr[i+1] = carry + wbase + s;
        int total = ws[15];
        __syncthreads();
        if(t==0) carrysh = carry + total;
        __syncthreads();
    }
}

__global__ void k_scatter(const int* __restrict__ dst, const int* __restrict__ rowptr,
                          int* __restrict__ cnt2, int* __restrict__ eid, int E){
    int e = blockIdx.x*256 + threadIdx.x;
    if(e >= E) return;
    int d = dst[e];
    int p = rowptr[d] + atomicAdd(&cnt2[d], 1);
    eid[p] = e;
}

__global__ __launch_bounds__(256) void k_sortb(const int* __restrict__ rowptr, int* __restrict__ eid, int n){
    int node = blockIdx.x*4 + (threadIdx.x>>6);
    if(node >= n) return;
    int lane = threadIdx.x & 63;
    int b = rowptr[node], e = rowptr[node+1];
    int nj = e - b;
    if(nj <= 1) return;
    if(nj <= 64){
        int v = (lane < nj) ? eid[b+lane] : 0x7fffffff;
        for(int k=2; k<=64; k<<=1){
            for(int j=k>>1; j>0; j>>=1){
                int vv = __shfl_xor(v, j, 64);
                bool up = ((lane & k) == 0);
                bool lower = ((lane & j) == 0);
                int mn = min(v,vv), mx = max(v,vv);
                v = (lower == up) ? mn : mx;
            }
        }
        if(lane < nj) eid[b+lane] = v;
    } else if(lane == 0){
        for(int i=b+1; i<e; i++){
            int key = eid[i]; int j = i-1;
            while(j>=b && eid[j] > key){ eid[j+1] = eid[j]; j--; }
            eid[j+1] = key;
        }
    }
}

// T[l][a] = emb[a] . wvec[l]
__global__ __launch_bounds__(768) void k_table(const float* __restrict__ We, const float* __restrict__ atte,
                                               const float* __restrict__ emb, float* __restrict__ T){
    __shared__ float wv[768];
    int t = threadIdx.x;
    {
        int l = t>>7, k = t&127;
        const float* w = We + ((size_t)l*128 + k)*64;
        const float* a = atte + l*64;
        float s = 0.f;
        #pragma unroll 8
        for(int c=0;c<64;c++) s += w[c]*a[c];
        wv[t] = s;
    }
    __syncthreads();
    int l = t>>7, a = t&127;
    const float4* er = (const float4*)(emb + (size_t)a*128);
    const float* w = wv + l*128;
    float acc = 0.f;
    for(int k=0;k<32;k++){
        float4 v = er[k];
        acc += v.x*w[k*4+0] + v.y*w[k*4+1] + v.z*w[k*4+2] + v.w*w[k*4+3];
    }
    T[l*128 + a] = acc;
}

// fill csrsrc + ae[l][p] by table lookup (pure gather)
__global__ __launch_bounds__(256) void k_ae2(const int* __restrict__ eid, const int* __restrict__ src,
                     const int* __restrict__ eattr, const float* __restrict__ T,
                     int* __restrict__ csrsrc, float* __restrict__ ae, int E){
    __shared__ float Tl[768];
    for(int i=threadIdx.x; i<768; i+=256) Tl[i] = T[i];
    __syncthreads();
    int p = blockIdx.x*256 + threadIdx.x;
    if(p >= E) return;
    int e = eid[p];
    csrsrc[p] = src[e];
    int a = eattr[e];
    #pragma unroll
    for(int l=0;l<6;l++) ae[(size_t)l*E + p] = Tl[l*128 + a];
}

// Wcomb[l] = W3[l] @ Wn[l+1]; bcomb[l] = b3[l] @ Wn[l+1]
__global__ __launch_bounds__(64) void k_wcomb(const float* __restrict__ W3all, const float* __restrict__ Wnall,
                                              const float* __restrict__ b3all,
                                              float* __restrict__ Wcomb, float* __restrict__ bcomb){
    int bid = blockIdx.x;
    int l = bid / 65, r = bid % 65;
    const float* Wn = Wnall + (size_t)(l+1)*8192;
    int c = threadIdx.x;
    if(r < 64){
        const float* w3r = W3all + (size_t)l*8192 + r*128;
        float s = 0.f;
        for(int j=0;j<128;j++) s += w3r[j]*Wn[j*64+c];
        Wcomb[l*4096 + r*64 + c] = s;
    } else {
        const float* b3 = b3all + l*128;
        float s = 0.f;
        for(int j=0;j<128;j++) s += b3[j]*Wn[j*64+c];
        bcomb[l*64+c] = s;
    }
}

// hemb[a][c] = emb[a] @ conv_W[0] — thread = (a,c), sequential-k fma chain (bit-exact per element)
__global__ __launch_bounds__(256) void k_hemb(const float* __restrict__ emb, const float* __restrict__ W0,
                                              float* __restrict__ hemb){
    int idx = blockIdx.x*256 + threadIdx.x;   // 0..8191
    int a = idx>>6, c = idx&63;
    const float* er = emb + (size_t)a*128;
    float acc = 0.f;
    for(int k=0;k<128;k++) acc = fmaf(er[k], W0[k*64 + c], acc);
    hemb[a*64 + c] = acc;
}

// aS[a]/aD[a] with the old k_hx's 8-chunk reduction order (bit-exact)
__global__ __launch_bounds__(128) void k_aemb(const float* __restrict__ hemb,
                                              const float* __restrict__ atts, const float* __restrict__ attd,
                                              float* __restrict__ aS, float* __restrict__ aD){
    int a = threadIdx.x;
    const float* hr = hemb + a*64;
    float sa = 0.f, sd = 0.f;
    for(int w=0;w<8;w++){
        float pa = 0.f, pd = 0.f;
        #pragma unroll
        for(int cc=0;cc<8;cc++){
            int c = w*8+cc;
            pa += hr[c]*atts[c];
            pd += hr[c]*attd[c];
        }
        sa += pa; sd += pd;
    }
    aS[a] = sa; aD[a] = sd;
}

// layer-0 h: pure gather from hemb/aS/aD
__global__ void k_hx2(const int* __restrict__ xidx, const float* __restrict__ hemb,
                      const float* __restrict__ aS, const float* __restrict__ aD,
                      float* __restrict__ h, float* __restrict__ as_, float* __restrict__ ad_, int n){
    int idx = blockIdx.x*256 + threadIdx.x;
    if(idx >= n*16) return;
    int node = idx>>4, q = idx&15, c0 = q*4;
    int xi = xidx[node];
    *(float4*)(h + (size_t)node*64 + c0) = *(const float4*)(hemb + (size_t)xi*64 + c0);
    if(q==0){ as_[node] = aS[xi]; ad_[node] = aD[xi]; }
}

// ---------------- GAT aggregation: wave per node ----------------

__global__ __launch_bounds__(256) void k_gat(const float* __restrict__ h,
        const float* __restrict__ as_, const float* __restrict__ ad_,
        const float* __restrict__ ae, const int* __restrict__ rowptr,
        const int* __restrict__ csrsrc, const float* __restrict__ bias,
        float* __restrict__ o, int n){
    int node = blockIdx.x*4 + (threadIdx.x>>6);
    if(node >= n) return;
    int lane = threadIdx.x & 63;
    int b = rowptr[node], e = rowptr[node+1];
    float adv = ad_[node];
    float m = -1e30f, d = 0.f, sumae = 0.f;
    float a0=0.f, a1=0.f, a2=0.f, a3=0.f;
    for(int j0=b; j0<e; j0+=64){
        int nj = min(64, e-j0);
        int sj = 0; float aev = 0.f, lg = -1e30f;
        if(lane < nj){
            sj  = csrsrc[j0+lane];
            aev = ae[j0+lane];
            lg  = lrelu(as_[sj] + adv + aev);
        }
        float cm = lg, sa = aev;
        #pragma unroll
        for(int off=32; off; off>>=1){ cm = fmaxf(cm, __shfl_xor(cm,off,64)); sa += __shfl_xor(sa,off,64); }
        sumae += sa;
        float nm = fmaxf(m, cm);
        float w = (lane<nj) ? expf(lg-nm) : 0.f;
        float ws = w;
        #pragma unroll
        for(int off=32; off; off>>=1) ws += __shfl_xor(ws,off,64);
        float scale = (m > -1e29f) ? expf(m-nm) : 0.f;
        d = d*scale + ws;
        a0*=scale; a1*=scale; a2*=scale; a3*=scale;
        int j = 0;
        for(; j+3<nj; j+=4){
            a0 = fmaf(bcastf(w,j+0), h[(size_t)__builtin_amdgcn_readlane(sj,j+0)*64 + lane], a0);
            a1 = fmaf(bcastf(w,j+1), h[(size_t)__builtin_amdgcn_readlane(sj,j+1)*64 + lane], a1);
            a2 = fmaf(bcastf(w,j+2), h[(size_t)__builtin_amdgcn_readlane(sj,j+2)*64 + lane], a2);
            a3 = fmaf(bcastf(w,j+3), h[(size_t)__builtin_amdgcn_readlane(sj,j+3)*64 + lane], a3);
        }
        for(; j<nj; j++)
            a0 = fmaf(bcastf(w,j), h[(size_t)__builtin_amdgcn_readlane(sj,j)*64 + lane], a0);
        m = nm;
    }
    int deg = e - b;
    float ael = sumae / fmaxf((float)deg, 1.f);
    float ls = lrelu(as_[node] + adv + ael);
    float nm = fmaxf(m, ls);
    float scale = (m > -1e29f) ? expf(m-nm) : 0.f;
    float wl = expf(ls-nm);
    d = d*scale + wl;
    float acc = (a0+a1)+(a2+a3);
    acc = acc*scale + wl*h[(size_t)node*64 + lane];
    o[(size_t)node*64 + lane] = acc/d + bias[lane];
}

// ---------------- dense: MLP3 + JKN + fused next-layer h via Wcomb ----------------

__global__ __launch_bounds__(512) void k_dense(
    const float* __restrict__ o,
    const float* __restrict__ W1, const float* __restrict__ b1,
    const float* __restrict__ W2, const float* __restrict__ b2,
    const float* __restrict__ W3, const float* __restrict__ b3,
    float* __restrict__ bestF, float* __restrict__ bestMs, int layer,
    const float* __restrict__ Wc, const float* __restrict__ bc,
    const float* __restrict__ atts, const float* __restrict__ attd,
    float* __restrict__ hn, float* __restrict__ asn, float* __restrict__ adn_,
    const float* __restrict__ A, const float* __restrict__ g1b1,
    const float* __restrict__ w2, const float* __restrict__ g1b2,
    const float* __restrict__ B, const float* __restrict__ g2b1,
    const float* __restrict__ C, const float* __restrict__ g2b2,
    float* __restrict__ h1, float* __restrict__ h2,
    int n, int last)
{
    __shared__ float o_s[64][65];
    __shared__ float xs[64][129];
    __shared__ float redA[8][64], redB[8][64];
    __shared__ unsigned char updf[64];
    int base = blockIdx.x*64;
    int t = threadIdx.x, lane = t & 63;
    int wid = __builtin_amdgcn_readfirstlane(t >> 6);

    {   // stage o tile (coalesced)
        int r = t>>3, c0 = (t&7)*8;
        if(base + r < n){
            const float4* srcp = (const float4*)(o + (size_t)(base+r)*64 + c0);
            float4 v0 = srcp[0], v1 = srcp[1];
            o_s[r][c0+0]=v0.x; o_s[r][c0+1]=v0.y; o_s[r][c0+2]=v0.z; o_s[r][c0+3]=v0.w;
            o_s[r][c0+4]=v1.x; o_s[r][c0+5]=v1.y; o_s[r][c0+6]=v1.z; o_s[r][c0+7]=v1.w;
        } else {
            #pragma unroll
            for(int q=0;q<8;q++) o_s[r][c0+q] = 0.f;
        }
    }
    __syncthreads();

    // ---- B: t1 = relu(o @ W1 + b1) -> xs cols 0..63
    {
        int cb = wid*8;
        float acc[8];
        #pragma unroll
        for(int cc=0;cc<8;cc++) acc[cc] = b1[cb+cc];
        for(int k=0;k<64;k++){
            float ov = o_s[lane][k];
            #pragma unroll
            for(int cc=0;cc<8;cc++) acc[cc] = fmaf(ov, W1[k*64 + cb + cc], acc[cc]);
        }
        #pragma unroll
        for(int cc=0;cc<8;cc++) xs[lane][cb+cc] = fmaxf(acc[cc], 0.f);
    }
    __syncthreads();

    // ---- C: t2 = relu(t1 @ W2 + b2) -> o_s (reuse)
    {
        int cb = wid*8;
        float acc[8];
        #pragma unroll
        for(int cc=0;cc<8;cc++) acc[cc] = b2[cb+cc];
        for(int k=0;k<64;k++){
            float tv = xs[lane][k];
            #pragma unroll
            for(int cc=0;cc<8;cc++) acc[cc] = fmaf(tv, W2[k*64 + cb + cc], acc[cc]);
        }
        __syncthreads();
        #pragma unroll
        for(int cc=0;cc<8;cc++) o_s[lane][cb+cc] = fmaxf(acc[cc], 0.f);
    }
    __syncthreads();

    // ---- D: x' = t2 @ W3 + b3 (128 out, 16/lane) -> xs; ms partial
    {
        int cb = wid*16;
        float acc[16];
        #pragma unroll
        for(int cc=0;cc<16;cc++) acc[cc] = b3[cb+cc];
        for(int k=0;k<64;k++){
            float tv = o_s[lane][k];
            #pragma unroll
            for(int cc=0;cc<16;cc++) acc[cc] = fmaf(tv, W3[k*128 + cb + cc], acc[cc]);
        }
        float ms = 0.f;
        #pragma unroll
        for(int cc=0;cc<16;cc++){ xs[lane][cb+cc] = acc[cc]; ms += acc[cc]*acc[cc]; }
        redA[wid][lane] = ms;
    }
    __syncthreads();

    // ---- JKN decision
    if(t < 64){
        int node = base + t; bool u = false;
        if(node < n){
            float ms = 0.f;
            #pragma unroll
            for(int w=0;w<8;w++) ms += redA[w][t];
            u = (layer==0) || (ms > bestMs[node]);
            if(u) bestMs[node] = ms;
        }
        updf[t] = u ? 1 : 0;
    }
    __syncthreads();

    if(!last){
        {   // conditional bestF row copy
            int r = t>>3, c0 = (t&7)*16;
            if(updf[r] && base + r < n){
                float* dst = bestF + (size_t)(base+r)*128 + c0;
                #pragma unroll
                for(int q=0;q<16;q++) dst[q] = xs[r][c0+q];
            }
        }
        // ---- F (fused): h_next = t2 @ Wcomb + bcomb (k=64, reads o_s) + a_s/a_d
        {
            int cb = wid*8;
            float acc[8];
            #pragma unroll
            for(int cc=0;cc<8;cc++) acc[cc] = bc[cb+cc];
            for(int k=0;k<64;k++){
                float tv = o_s[lane][k];
                #pragma unroll
                for(int cc=0;cc<8;cc++) acc[cc] = fmaf(tv, Wc[k*64 + cb + cc], acc[cc]);
            }
            float pa=0.f, pd=0.f;
            #pragma unroll
            for(int cc=0;cc<8;cc++){
                pa += acc[cc]*atts[cb+cc];
                pd += acc[cc]*attd[cb+cc];
            }
            redA[wid][lane]=pa; redB[wid][lane]=pd;
            __syncthreads();          // all waves done READING o_s (t2)
            #pragma unroll
            for(int cc=0;cc<8;cc++) o_s[lane][cb+cc] = acc[cc];
        }
        __syncthreads();
        {
            int r = t>>3, c0 = (t&7)*8;
            if(base + r < n){
                float* dst = hn + (size_t)(base+r)*64 + c0;
                #pragma unroll
                for(int q=0;q<8;q++) dst[q] = o_s[r][c0+q];
            }
        }
        if(t < 64 && base + t < n){
            float sa=0.f, sd=0.f;
            #pragma unroll
            for(int w=0;w<8;w++){ sa += redA[w][t]; sd += redB[w][t]; }
            asn[base+t] = sa; adn_[base+t] = sd;
        }
        return;
    }

    // ================= last layer: fused pooling GEMMs =================
    {
        int r = t>>3, c0 = (t&7)*16;
        if(!updf[r] && base + r < n){
            const float4* srcp = (const float4*)(bestF + (size_t)(base+r)*128 + c0);
            #pragma unroll
            for(int q=0;q<4;q++){
                float4 v = srcp[q];
                xs[r][c0+q*4+0]=v.x; xs[r][c0+q*4+1]=v.y; xs[r][c0+q*4+2]=v.z; xs[r][c0+q*4+3]=v.w;
            }
        }
    }
    __syncthreads();
    if(wid < 4){
        int cb = wid*16;
        float acc[16];
        #pragma unroll
        for(int cc=0;cc<16;cc++) acc[cc] = g1b1[cb+cc];
        for(int k=0;k<128;k++){
            float fv = xs[lane][k];
            #pragma unroll
            for(int cc=0;cc<16;cc++) acc[cc] = fmaf(fv, A[k*64 + cb + cc], acc[cc]);
        }
        float pp = 0.f;
        #pragma unroll
        for(int cc=0;cc<16;cc++) pp += fmaxf(acc[cc],0.f)*w2[cb+cc];
        redA[wid][lane] = pp;
    } else {
        int cb = (wid-4)*16;
        float acc[16];
        #pragma unroll
        for(int cc=0;cc<16;cc++) acc[cc] = g2b1[cb+cc];
        for(int k=0;k<128;k++){
            float fv = xs[lane][k];
            #pragma unroll
            for(int cc=0;cc<16;cc++) acc[cc] = fmaf(fv, B[k*64 + cb + cc], acc[cc]);
        }
        #pragma unroll
        for(int cc=0;cc<16;cc++) o_s[lane][cb+cc] = fmaxf(acc[cc],0.f);
    }
    __syncthreads();
    if(t < 64 && base + t < n)
        h1[base+t] = redA[0][t]+redA[1][t]+redA[2][t]+redA[3][t] + g1b2[0];
    {
        int cb = wid*16;
        float acc[16];
        #pragma unroll
        for(int cc=0;cc<16;cc++) acc[cc] = g2b2[cb+cc];
        for(int k=0;k<64;k++){
            float tv = o_s[lane][k];
            #pragma unroll
            for(int cc=0;cc<16;cc++) acc[cc] = fmaf(tv, C[k*128 + cb + cc], acc[cc]);
        }
        __syncthreads();
        #pragma unroll
        for(int cc=0;cc<16;cc++) xs[lane][cb+cc] = acc[cc];
    }
    __syncthreads();
    {
        int r = t>>3, c0 = (t&7)*16;
        if(base + r < n){
            float* dst = h2 + (size_t)(base+r)*128 + c0;
            #pragma unroll
            for(int q=0;q<16;q++) dst[q] = xs[r][c0+q];
        }
    }
}

// ---------------- pooling softmax + per-graph prediction MLP ----------------

__global__ __launch_bounds__(128) void k_pool2(const float* __restrict__ h1, const float* __restrict__ h2,
                      float* __restrict__ wbuf,
                      const float* __restrict__ pW1, const float* __restrict__ pb1,
                      const float* __restrict__ pW2, const float* __restrict__ pb2,
                      const float* __restrict__ pW3, const float* __restrict__ pb3,
                      float* __restrict__ out, int n, int G){
    __shared__ float sh[128];
    __shared__ float hgrow[128];
    int g = blockIdx.x, tid = threadIdx.x;
    int start = (g*n + G-1)/G, end = ((g+1)*n + G-1)/G;
    float lm = -1e30f;
    for(int i=start+tid; i<end; i+=128) lm = fmaxf(lm, h1[i]);
    sh[tid]=lm; __syncthreads();
    for(int off=64; off; off>>=1){ if(tid<off) sh[tid]=fmaxf(sh[tid],sh[tid+off]); __syncthreads(); }
    float m = sh[0]; __syncthreads();
    float lsum = 0.f;
    for(int i=start+tid; i<end; i+=128){ float w = expf(h1[i]-m); wbuf[i]=w; lsum+=w; }
    sh[tid]=lsum; __syncthreads();
    for(int off=64; off; off>>=1){ if(tid<off) sh[tid]+=sh[tid+off]; __syncthreads(); }
    float denom = sh[0];
    float a0=0.f,a1=0.f,a2=0.f,a3=0.f;
    int i = start;
    for(; i+3<end; i+=4){
        a0 = fmaf(wbuf[i+0], h2[(size_t)(i+0)*128 + tid], a0);
        a1 = fmaf(wbuf[i+1], h2[(size_t)(i+1)*128 + tid], a1);
        a2 = fmaf(wbuf[i+2], h2[(size_t)(i+2)*128 + tid], a2);
        a3 = fmaf(wbuf[i+3], h2[(size_t)(i+3)*128 + tid], a3);
    }
    for(; i<end; i++) a0 = fmaf(wbuf[i], h2[(size_t)i*128 + tid], a0);
    float acc = (a0+a1)+(a2+a3);
    hgrow[tid] = acc/denom/(float)(end-start);
    __syncthreads();
    if(tid < 64){
        float t1v = pb1[tid];
        for(int k=0;k<128;k++) t1v = fmaf(hgrow[k], pW1[k*64+tid], t1v);
        t1v = fmaxf(t1v, 0.f);
        float t2v = pb2[tid];
        for(int k=0;k<64;k++) t2v = fmaf(__shfl(t1v,k,64), pW2[k*64+tid], t2v);
        t2v = fmaxf(t2v, 0.f);
        float s = t2v * pW3[tid];
        #pragma unroll
        for(int off=32; off; off>>=1) s += __shfl_xor(s,off,64);
        if(tid==0) out[g] = s + pb3[0];
    }
}

extern "C" void kernel_launch(void* const* d_in, const int* in_sizes, int n_in,
                              void* d_out, int out_size, void* d_ws, size_t ws_size,
                              hipStream_t stream){
    const int*   x_idx   = (const int*)  d_in[0];
    const int*   eindex  = (const int*)  d_in[1];
    const int*   eattr   = (const int*)  d_in[2];
    const float* emb     = (const float*)d_in[4];
    const float* conv_W  = (const float*)d_in[5];
    const float* conv_We = (const float*)d_in[6];
    const float* att_src = (const float*)d_in[7];
    const float* att_dst = (const float*)d_in[8];
    const float* att_edg = (const float*)d_in[9];
    const float* conv_b  = (const float*)d_in[10];
    const float* mW1 = (const float*)d_in[11]; const float* mb1 = (const float*)d_in[12];
    const float* mW2 = (const float*)d_in[13]; const float* mb2 = (const float*)d_in[14];
    const float* mW3 = (const float*)d_in[15]; const float* mb3 = (const float*)d_in[16];
    const float* g1W1= (const float*)d_in[17]; const float* g1b1= (const float*)d_in[18];
    const float* g1W2= (const float*)d_in[19]; const float* g1b2= (const float*)d_in[20];
    const float* g2W1= (const float*)d_in[21]; const float* g2b1= (const float*)d_in[22];
    const float* g2W2= (const float*)d_in[23]; const float* g2b2= (const float*)d_in[24];
    const float* pW1 = (const float*)d_in[25]; const float* pb1 = (const float*)d_in[26];
    const float* pW2 = (const float*)d_in[27]; const float* pb2 = (const float*)d_in[28];
    const float* pW3 = (const float*)d_in[29]; const float* pb3 = (const float*)d_in[30];

    const int N = in_sizes[0];
    const int E = in_sizes[2];
    const int G = out_size;
    const int* src = eindex;
    const int* dst = eindex + E;
    const int NT = (N + 63) / 64;
    const int NW = (N + 3) / 4;

    char* p = (char*)d_ws;
    auto alloc = [&](size_t bytes)->void*{ void* r = (void*)p; p += (bytes + 255) & ~(size_t)255; return r; };
    float* h      = (float*)alloc((size_t)N*64*4);
    float* o      = (float*)alloc((size_t)N*64*4);
    float* bestF  = (float*)alloc((size_t)N*128*4);
    float* h2buf  = (float*)alloc((size_t)N*128*4);
    float* bestMs = (float*)alloc((size_t)N*4);
    float* as_    = (float*)alloc((size_t)N*4);
    float* ad_    = (float*)alloc((size_t)N*4);
    float* ae     = (float*)alloc((size_t)6*E*4);
    float* Tbuf   = (float*)alloc(6*128*4);
    float* h1     = (float*)alloc((size_t)N*4);
    float* Wcomb  = (float*)alloc(5*4096*4);
    float* bcomb  = (float*)alloc(5*64*4);
    float* hemb   = (float*)alloc(128*64*4);
    float* aS     = (float*)alloc(128*4);
    float* aD     = (float*)alloc(128*4);
    int*   cnt    = (int*)  alloc((size_t)N*4);
    int*   cnt2   = (int*)  alloc((size_t)N*4);
    int*   rowptr = (int*)  alloc((size_t)(N+1)*4);
    int*   eid    = (int*)  alloc((size_t)E*4);
    int*   csrsrc = (int*)  alloc((size_t)E*4);

    hipMemsetAsync(cnt,  0, (size_t)N*4, stream);
    hipMemsetAsync(cnt2, 0, (size_t)N*4, stream);

    k_count<<<(E+255)/256, 256, 0, stream>>>(dst, cnt, E);
    k_scan<<<1, 1024, 0, stream>>>(cnt, rowptr, N);
    k_scatter<<<(E+255)/256, 256, 0, stream>>>(dst, rowptr, cnt2, eid, E);
    k_sortb<<<NW, 256, 0, stream>>>(rowptr, eid, N);
    k_table<<<1, 768, 0, stream>>>(conv_We, att_edg, emb, Tbuf);
    k_ae2<<<(E+255)/256, 256, 0, stream>>>(eid, src, eattr, Tbuf, csrsrc, ae, E);
    k_wcomb<<<5*65, 64, 0, stream>>>(mW3, conv_W, mb3, Wcomb, bcomb);
    k_hemb<<<32, 256, 0, stream>>>(emb, conv_W, hemb);
    k_aemb<<<1, 128, 0, stream>>>(hemb, att_src, att_dst, aS, aD);
    k_hx2<<<(N*16+255)/256, 256, 0, stream>>>(x_idx, hemb, aS, aD, h, as_, ad_, N);

    for(int l=0; l<6; l++){
        int last = (l==5) ? 1 : 0;
        const float* Wc   = last ? Wcomb : Wcomb + (size_t)l*4096;
        const float* bcp  = last ? bcomb : bcomb + (size_t)l*64;
        const float* atsn = last ? att_src : att_src + (l+1)*64;
        const float* atdn = last ? att_dst : att_dst + (l+1)*64;
        k_gat<<<NW, 256, 0, stream>>>(h, as_, ad_, ae + (size_t)l*E, rowptr, csrsrc, conv_b + l*64, o, N);
        k_dense<<<NT, 512, 0, stream>>>(o,
            mW1 + (size_t)l*4096, mb1 + l*64, mW2 + (size_t)l*4096, mb2 + l*64,
            mW3 + (size_t)l*8192, mb3 + l*128,
            bestF, bestMs, l,
            Wc, bcp, atsn, atdn,
            h, as_, ad_,
            g1W1, g1b1, g1W2, g1b2, g2W1, g2b1, g2W2, g2b2,
            h1, h2buf,
            N, last);
    }

    k_pool2<<<G, 128, 0, stream>>>(h1, h2buf, bestMs,
            pW1, pb1, pW2, pb2, pW3, pb3, (float*)d_out, N, G);
}